// Round 1
// baseline (2663.433 us; speedup 1.0000x reference)
//
#include <hip/hip_runtime.h>
#include <hip/hip_bf16.h>

// Problem constants (from reference): B=2, T=2048, C=1024, H=16, D=64
#define BSZ 2
#define SEQ 2048
#define CDIM 1024
#define NHEAD 16
#define HDIM 64
#define M_GEMM (BSZ * SEQ)      // 4096
#define N_GEMM (3 * CDIM)       // 3072
#define K_GEMM CDIM             // 1024

// ---------------- Kernel 1: qkv = x @ W + b (fp32, LDS-tiled) ----------------
#define BM 128
#define BN 128
#define BK 16

__global__ __launch_bounds__(256) void qkv_gemm(const float* __restrict__ X,
                                                const float* __restrict__ W,
                                                const float* __restrict__ bias,
                                                float* __restrict__ Y) {
    __shared__ float As[BK][BM];   // A stored transposed: As[k][m]
    __shared__ float Bs[BK][BN];

    const int tid = threadIdx.x;
    const int tx = tid & 15;        // 0..15 -> cols
    const int ty = tid >> 4;        // 0..15 -> rows
    const int m0 = blockIdx.y * BM;
    const int n0 = blockIdx.x * BN;

    float acc[8][8];
#pragma unroll
    for (int i = 0; i < 8; ++i)
#pragma unroll
        for (int j = 0; j < 8; ++j) acc[i][j] = 0.f;

    for (int kt = 0; kt < K_GEMM; kt += BK) {
        // Load A tile: 128 rows x 16 k = 512 float4
#pragma unroll
        for (int q = 0; q < 2; ++q) {
            int i = q * 256 + tid;          // 0..511
            int row = i >> 2;               // 0..127
            int cf = i & 3;                 // 0..3
            float4 a = *(const float4*)&X[(m0 + row) * K_GEMM + kt + cf * 4];
            As[cf * 4 + 0][row] = a.x;
            As[cf * 4 + 1][row] = a.y;
            As[cf * 4 + 2][row] = a.z;
            As[cf * 4 + 3][row] = a.w;
        }
        // Load B tile: 16 rows x 128 cols = 512 float4 (coalesced along N)
#pragma unroll
        for (int q = 0; q < 2; ++q) {
            int i = q * 256 + tid;
            int row = i >> 5;               // 0..15
            int cf = i & 31;                // 0..31
            *(float4*)&Bs[row][cf * 4] =
                *(const float4*)&W[(kt + row) * N_GEMM + n0 + cf * 4];
        }
        __syncthreads();

#pragma unroll
        for (int k = 0; k < BK; ++k) {
            float a[8], b[8];
            *(float4*)&a[0] = *(const float4*)&As[k][ty * 8];
            *(float4*)&a[4] = *(const float4*)&As[k][ty * 8 + 4];
            *(float4*)&b[0] = *(const float4*)&Bs[k][tx * 8];
            *(float4*)&b[4] = *(const float4*)&Bs[k][tx * 8 + 4];
#pragma unroll
            for (int i = 0; i < 8; ++i)
#pragma unroll
                for (int j = 0; j < 8; ++j) acc[i][j] += a[i] * b[j];
        }
        __syncthreads();
    }

#pragma unroll
    for (int i = 0; i < 8; ++i) {
        int m = m0 + ty * 8 + i;
#pragma unroll
        for (int jv = 0; jv < 2; ++jv) {
            int n = n0 + tx * 8 + jv * 4;
            float4 o;
            o.x = acc[i][jv * 4 + 0] + bias[n + 0];
            o.y = acc[i][jv * 4 + 1] + bias[n + 1];
            o.z = acc[i][jv * 4 + 2] + bias[n + 2];
            o.w = acc[i][jv * 4 + 3] + bias[n + 3];
            *(float4*)&Y[m * N_GEMM + n] = o;
        }
    }
}

// ------------- Kernel 2: causal flash attention (fp32, 1 wave/block) ---------
// grid: (SEQ/64, NHEAD, BSZ), block: 64 threads. Thread t owns query row qt*64+t.
__global__ __launch_bounds__(64) void attn_flash(const float* __restrict__ qkv,
                                                 float* __restrict__ out) {
    const int b = blockIdx.z;
    const int h = blockIdx.y;
    const int qt = blockIdx.x;
    const int t = threadIdx.x;
    const int q_row = qt * 64 + t;

    __shared__ float Ks[64][64];    // [key][d]
    __shared__ float Vs[64][64];    // [key][d]
    __shared__ float Ss[64][65];    // [thread][key], padded: banks (t+j)%32

    const float scale = 0.125f;     // 1/sqrt(64)

    // Load this thread's query row into registers
    const float* qptr = qkv + (b * SEQ + q_row) * N_GEMM + h * HDIM;
    float qreg[64];
#pragma unroll
    for (int d4 = 0; d4 < 16; ++d4) {
        float4 v = *(const float4*)&qptr[d4 * 4];
        qreg[d4 * 4 + 0] = v.x;
        qreg[d4 * 4 + 1] = v.y;
        qreg[d4 * 4 + 2] = v.z;
        qreg[d4 * 4 + 3] = v.w;
    }

    float mrun = -1e30f;
    float lrun = 0.f;
    float o[64];
#pragma unroll
    for (int d = 0; d < 64; ++d) o[d] = 0.f;

    for (int kt = 0; kt <= qt; ++kt) {
        // Cooperative K/V tile load: 64 keys x 64 d. Lane groups of 16 read
        // 256B contiguous -> coalesced.
        const float* kbase = qkv + (b * SEQ + kt * 64) * N_GEMM + CDIM + h * HDIM;
        const float* vbase = kbase + CDIM;
#pragma unroll
        for (int q = 0; q < 16; ++q) {
            int i = q * 64 + t;        // 0..1023
            int j = i >> 4;            // key row 0..63
            int d4 = i & 15;           // float4 index
            *(float4*)&Ks[j][d4 * 4] = *(const float4*)&kbase[j * N_GEMM + d4 * 4];
            *(float4*)&Vs[j][d4 * 4] = *(const float4*)&vbase[j * N_GEMM + d4 * 4];
        }
        __syncthreads();

        // Pass 1: scores for this row vs 64 keys; track running max
        float smax = mrun;
        for (int j = 0; j < 64; ++j) {
            float s = 0.f;
#pragma unroll
            for (int d4 = 0; d4 < 16; ++d4) {
                float4 kv = *(const float4*)&Ks[j][d4 * 4];  // wave-uniform broadcast
                s += qreg[d4 * 4 + 0] * kv.x + qreg[d4 * 4 + 1] * kv.y +
                     qreg[d4 * 4 + 2] * kv.z + qreg[d4 * 4 + 3] * kv.w;
            }
            s *= scale;
            int kj = kt * 64 + j;
            s = (kj <= q_row) ? s : -1e30f;   // causal mask
            smax = fmaxf(smax, s);
            Ss[t][j] = s;
        }

        // Online softmax rescale
        float corr = __expf(mrun - smax);
        lrun *= corr;
#pragma unroll
        for (int d = 0; d < 64; ++d) o[d] *= corr;

        // Pass 2: p = exp(s - smax); o += p * V
        for (int j = 0; j < 64; ++j) {
            float p = __expf(Ss[t][j] - smax);
            lrun += p;
#pragma unroll
            for (int d4 = 0; d4 < 16; ++d4) {
                float4 vv = *(const float4*)&Vs[j][d4 * 4];  // wave-uniform broadcast
                o[d4 * 4 + 0] += p * vv.x;
                o[d4 * 4 + 1] += p * vv.y;
                o[d4 * 4 + 2] += p * vv.z;
                o[d4 * 4 + 3] += p * vv.w;
            }
        }
        mrun = smax;
        __syncthreads();   // before next tile overwrites Ks/Vs
    }

    float inv = 1.f / lrun;
    float* optr = out + (b * SEQ + q_row) * CDIM + h * HDIM;
#pragma unroll
    for (int d4 = 0; d4 < 16; ++d4) {
        float4 vv;
        vv.x = o[d4 * 4 + 0] * inv;
        vv.y = o[d4 * 4 + 1] * inv;
        vv.z = o[d4 * 4 + 2] * inv;
        vv.w = o[d4 * 4 + 3] * inv;
        *(float4*)&optr[d4 * 4] = vv;
    }
}

// ------------------------------- launch --------------------------------------
extern "C" void kernel_launch(void* const* d_in, const int* in_sizes, int n_in,
                              void* d_out, int out_size, void* d_ws, size_t ws_size,
                              hipStream_t stream) {
    const float* x      = (const float*)d_in[0];   // [B,T,C]
    const float* w_attn = (const float*)d_in[1];   // [C,3C]
    const float* b_attn = (const float*)d_in[2];   // [3C]
    float* out = (float*)d_out;                    // [B,T,C]
    float* qkv = (float*)d_ws;                     // [B,T,3C] = 50.3 MB scratch

    // Kernel 1: qkv GEMM
    dim3 g1(N_GEMM / BN, M_GEMM / BM);   // (24, 32)
    qkv_gemm<<<g1, 256, 0, stream>>>(x, w_attn, b_attn, qkv);

    // Kernel 2: causal flash attention
    dim3 g2(SEQ / 64, NHEAD, BSZ);       // (32, 16, 2)
    attn_flash<<<g2, 64, 0, stream>>>(qkv, out);
}

// Round 2
// 2503.900 us; speedup vs baseline: 1.0637x; 1.0637x over previous
//
#include <hip/hip_runtime.h>
#include <hip/hip_bf16.h>

// Problem constants (from reference): B=2, T=2048, C=1024, H=16, D=64
#define BSZ 2
#define SEQ 2048
#define CDIM 1024
#define NHEAD 16
#define HDIM 64
#define M_GEMM (BSZ * SEQ)      // 4096
#define N_GEMM (3 * CDIM)       // 3072
#define K_GEMM CDIM             // 1024

// ---------------- Kernel 1: qkv = x @ W + b (fp32, LDS-tiled) ----------------
#define BM 128
#define BN 128
#define BK 16

__global__ __launch_bounds__(256) void qkv_gemm(const float* __restrict__ X,
                                                const float* __restrict__ W,
                                                const float* __restrict__ bias,
                                                float* __restrict__ Y) {
    __shared__ float As[BK][BM];   // A stored transposed: As[k][m]
    __shared__ float Bs[BK][BN];

    const int tid = threadIdx.x;
    const int tx = tid & 15;        // 0..15 -> cols
    const int ty = tid >> 4;        // 0..15 -> rows
    const int m0 = blockIdx.y * BM;
    const int n0 = blockIdx.x * BN;

    float acc[8][8];
#pragma unroll
    for (int i = 0; i < 8; ++i)
#pragma unroll
        for (int j = 0; j < 8; ++j) acc[i][j] = 0.f;

    for (int kt = 0; kt < K_GEMM; kt += BK) {
        // Load A tile: 128 rows x 16 k = 512 float4
#pragma unroll
        for (int q = 0; q < 2; ++q) {
            int i = q * 256 + tid;          // 0..511
            int row = i >> 2;               // 0..127
            int cf = i & 3;                 // 0..3
            float4 a = *(const float4*)&X[(m0 + row) * K_GEMM + kt + cf * 4];
            As[cf * 4 + 0][row] = a.x;
            As[cf * 4 + 1][row] = a.y;
            As[cf * 4 + 2][row] = a.z;
            As[cf * 4 + 3][row] = a.w;
        }
        // Load B tile: 16 rows x 128 cols = 512 float4 (coalesced along N)
#pragma unroll
        for (int q = 0; q < 2; ++q) {
            int i = q * 256 + tid;
            int row = i >> 5;               // 0..15
            int cf = i & 31;                // 0..31
            *(float4*)&Bs[row][cf * 4] =
                *(const float4*)&W[(kt + row) * N_GEMM + n0 + cf * 4];
        }
        __syncthreads();

#pragma unroll
        for (int k = 0; k < BK; ++k) {
            float a[8], b[8];
            *(float4*)&a[0] = *(const float4*)&As[k][ty * 8];
            *(float4*)&a[4] = *(const float4*)&As[k][ty * 8 + 4];
            *(float4*)&b[0] = *(const float4*)&Bs[k][tx * 8];
            *(float4*)&b[4] = *(const float4*)&Bs[k][tx * 8 + 4];
#pragma unroll
            for (int i = 0; i < 8; ++i)
#pragma unroll
                for (int j = 0; j < 8; ++j) acc[i][j] += a[i] * b[j];
        }
        __syncthreads();
    }

#pragma unroll
    for (int i = 0; i < 8; ++i) {
        int m = m0 + ty * 8 + i;
#pragma unroll
        for (int jv = 0; jv < 2; ++jv) {
            int n = n0 + tx * 8 + jv * 4;
            float4 o;
            o.x = acc[i][jv * 4 + 0] + bias[n + 0];
            o.y = acc[i][jv * 4 + 1] + bias[n + 1];
            o.z = acc[i][jv * 4 + 2] + bias[n + 2];
            o.w = acc[i][jv * 4 + 3] + bias[n + 3];
            *(float4*)&Y[m * N_GEMM + n] = o;
        }
    }
}

// ------------- Kernel 2: causal flash attention (fp32, restructured) ---------
// grid: (SEQ/128, NHEAD, BSZ) with heavy tiles first; block: 128 threads
// (2 waves). Thread t owns query row q0 + t. Scores held in an 8-register
// subtile (no LDS round-trip); online softmax amortized per 8 keys.
__global__ __launch_bounds__(128) void attn_flash(const float* __restrict__ qkv,
                                                  float* __restrict__ out) {
    const int b = blockIdx.z;
    const int h = blockIdx.y;
    const int qt = gridDim.x - 1 - blockIdx.x;   // heavy (long) tiles dispatch first
    const int t = threadIdx.x;                    // 0..127
    const int q0 = qt * 128;
    const int q_row = q0 + t;

    __shared__ float Ks[64][64];    // [key][d]
    __shared__ float Vs[64][64];    // [key][d]

    const float scale = 0.125f;     // 1/sqrt(64)

    // Load this thread's query row into registers (64 fp32)
    const float* qptr = qkv + (size_t)(b * SEQ + q_row) * N_GEMM + h * HDIM;
    float qreg[64];
#pragma unroll
    for (int d4 = 0; d4 < 16; ++d4) {
        float4 v = *(const float4*)&qptr[d4 * 4];
        qreg[d4 * 4 + 0] = v.x;
        qreg[d4 * 4 + 1] = v.y;
        qreg[d4 * 4 + 2] = v.z;
        qreg[d4 * 4 + 3] = v.w;
    }

    float mrun = -1e30f;
    float lrun = 0.f;
    float o[64];
#pragma unroll
    for (int d = 0; d < 64; ++d) o[d] = 0.f;

    // wave 0 owns rows q0..q0+63, wave 1 owns q0+64..q0+127
    const int wave_max_row = q0 + (t & 64) + 63;   // wave-uniform
    const int ktmax = (q0 + 127) >> 6;             // inclusive last key tile
    const float* kb0 = qkv + (size_t)(b * SEQ) * N_GEMM + CDIM + h * HDIM;

    for (int kt = 0; kt <= ktmax; ++kt) {
        const float* kbase = kb0 + (size_t)kt * 64 * N_GEMM;
        const float* vbase = kbase + CDIM;

        __syncthreads();   // previous tile's reads done before overwrite
        // Cooperative K/V tile load: 64 keys x 64 d each. 16 consecutive
        // lanes read 256B contiguous -> coalesced.
#pragma unroll
        for (int qq = 0; qq < 8; ++qq) {
            int i = qq * 128 + t;      // 0..1023
            int j = i >> 4;            // key row 0..63
            int d4 = i & 15;           // float4 index
            *(float4*)&Ks[j][d4 * 4] = *(const float4*)&kbase[(size_t)j * N_GEMM + d4 * 4];
            *(float4*)&Vs[j][d4 * 4] = *(const float4*)&vbase[(size_t)j * N_GEMM + d4 * 4];
        }
        __syncthreads();

        if (kt * 64 <= wave_max_row) {       // skip fully-masked tile (wave-uniform)
            const int kb_idx = kt * 64;
#pragma unroll 1
            for (int st = 0; st < 8; ++st) { // 8 keys per subtile, rolled (I-cache)
                float s[8];
                // QK: 8 scores into registers (broadcast LDS reads)
#pragma unroll
                for (int j = 0; j < 8; ++j) {
                    int row = st * 8 + j;
                    float acc = 0.f;
#pragma unroll
                    for (int d4 = 0; d4 < 16; ++d4) {
                        float4 kv = *(const float4*)&Ks[row][d4 * 4];
                        acc += qreg[d4 * 4 + 0] * kv.x + qreg[d4 * 4 + 1] * kv.y +
                               qreg[d4 * 4 + 2] * kv.z + qreg[d4 * 4 + 3] * kv.w;
                    }
                    int kj = kb_idx + st * 8 + j;
                    s[j] = (kj <= q_row) ? acc * scale : -1e30f;
                }
                // subtile max + online rescale
                float smax = s[0];
#pragma unroll
                for (int j = 1; j < 8; ++j) smax = fmaxf(smax, s[j]);
                float newmax = fmaxf(mrun, smax);
                float corr = __expf(mrun - newmax);
                lrun *= corr;
#pragma unroll
                for (int d = 0; d < 64; ++d) o[d] *= corr;
                // PV accumulate
#pragma unroll
                for (int j = 0; j < 8; ++j) {
                    float p = __expf(s[j] - newmax);
                    lrun += p;
                    int row = st * 8 + j;
#pragma unroll
                    for (int d4 = 0; d4 < 16; ++d4) {
                        float4 vv = *(const float4*)&Vs[row][d4 * 4];
                        o[d4 * 4 + 0] += p * vv.x;
                        o[d4 * 4 + 1] += p * vv.y;
                        o[d4 * 4 + 2] += p * vv.z;
                        o[d4 * 4 + 3] += p * vv.w;
                    }
                }
                mrun = newmax;
            }
        }
    }

    float inv = 1.f / lrun;
    float* optr = out + (size_t)(b * SEQ + q_row) * CDIM + h * HDIM;
#pragma unroll
    for (int d4 = 0; d4 < 16; ++d4) {
        float4 vv;
        vv.x = o[d4 * 4 + 0] * inv;
        vv.y = o[d4 * 4 + 1] * inv;
        vv.z = o[d4 * 4 + 2] * inv;
        vv.w = o[d4 * 4 + 3] * inv;
        *(float4*)&optr[d4 * 4] = vv;
    }
}

// ------------------------------- launch --------------------------------------
extern "C" void kernel_launch(void* const* d_in, const int* in_sizes, int n_in,
                              void* d_out, int out_size, void* d_ws, size_t ws_size,
                              hipStream_t stream) {
    const float* x      = (const float*)d_in[0];   // [B,T,C]
    const float* w_attn = (const float*)d_in[1];   // [C,3C]
    const float* b_attn = (const float*)d_in[2];   // [3C]
    float* out = (float*)d_out;                    // [B,T,C]
    float* qkv = (float*)d_ws;                     // [B,T,3C] = 50.3 MB scratch

    // Kernel 1: qkv GEMM
    dim3 g1(N_GEMM / BN, M_GEMM / BM);   // (24, 32)
    qkv_gemm<<<g1, 256, 0, stream>>>(x, w_attn, b_attn, qkv);

    // Kernel 2: causal flash attention
    dim3 g2(SEQ / 128, NHEAD, BSZ);      // (16, 16, 2)
    attn_flash<<<g2, 128, 0, stream>>>(qkv, out);
}

// Round 3
// 562.604 us; speedup vs baseline: 4.7341x; 4.4506x over previous
//
#include <hip/hip_runtime.h>
#include <hip/hip_bf16.h>

// Problem constants: B=2, T=2048, C=1024, H=16, D=64
#define BSZ 2
#define SEQ 2048
#define CDIM 1024
#define NHEAD 16
#define HDIM 64
#define M_GEMM (BSZ * SEQ)      // 4096
#define N_GEMM (3 * CDIM)       // 3072
#define K_GEMM CDIM             // 1024

typedef __attribute__((ext_vector_type(8))) short short8;   // 8 bf16 = 4 VGPR
typedef __attribute__((ext_vector_type(4))) short short4v;  // 8B
typedef __attribute__((ext_vector_type(4))) float f32x4;

__device__ __forceinline__ short bf16_rn(float f) {
    unsigned u = __builtin_bit_cast(unsigned, f);
    u += 0x7FFF + ((u >> 16) & 1);          // round-to-nearest-even
    return (short)(u >> 16);
}

// ---------------- Kernel 1: qkv = x @ W + b (fp32, LDS-tiled) ----------------
#define BM 128
#define BN 128
#define BK 16

__global__ __launch_bounds__(256) void qkv_gemm(const float* __restrict__ X,
                                                const float* __restrict__ W,
                                                const float* __restrict__ bias,
                                                float* __restrict__ Y) {
    __shared__ float As[BK][BM];
    __shared__ float Bs[BK][BN];

    const int tid = threadIdx.x;
    const int tx = tid & 15;
    const int ty = tid >> 4;
    const int m0 = blockIdx.y * BM;
    const int n0 = blockIdx.x * BN;

    float acc[8][8];
#pragma unroll
    for (int i = 0; i < 8; ++i)
#pragma unroll
        for (int j = 0; j < 8; ++j) acc[i][j] = 0.f;

    for (int kt = 0; kt < K_GEMM; kt += BK) {
#pragma unroll
        for (int q = 0; q < 2; ++q) {
            int i = q * 256 + tid;
            int row = i >> 2;
            int cf = i & 3;
            float4 a = *(const float4*)&X[(m0 + row) * K_GEMM + kt + cf * 4];
            As[cf * 4 + 0][row] = a.x;
            As[cf * 4 + 1][row] = a.y;
            As[cf * 4 + 2][row] = a.z;
            As[cf * 4 + 3][row] = a.w;
        }
#pragma unroll
        for (int q = 0; q < 2; ++q) {
            int i = q * 256 + tid;
            int row = i >> 5;
            int cf = i & 31;
            *(float4*)&Bs[row][cf * 4] =
                *(const float4*)&W[(kt + row) * N_GEMM + n0 + cf * 4];
        }
        __syncthreads();

#pragma unroll
        for (int k = 0; k < BK; ++k) {
            float a[8], b[8];
            *(float4*)&a[0] = *(const float4*)&As[k][ty * 8];
            *(float4*)&a[4] = *(const float4*)&As[k][ty * 8 + 4];
            *(float4*)&b[0] = *(const float4*)&Bs[k][tx * 8];
            *(float4*)&b[4] = *(const float4*)&Bs[k][tx * 8 + 4];
#pragma unroll
            for (int i = 0; i < 8; ++i)
#pragma unroll
                for (int j = 0; j < 8; ++j) acc[i][j] += a[i] * b[j];
        }
        __syncthreads();
    }

#pragma unroll
    for (int i = 0; i < 8; ++i) {
        int m = m0 + ty * 8 + i;
#pragma unroll
        for (int jv = 0; jv < 2; ++jv) {
            int n = n0 + tx * 8 + jv * 4;
            float4 o;
            o.x = acc[i][jv * 4 + 0] + bias[n + 0];
            o.y = acc[i][jv * 4 + 1] + bias[n + 1];
            o.z = acc[i][jv * 4 + 2] + bias[n + 2];
            o.w = acc[i][jv * 4 + 3] + bias[n + 3];
            *(float4*)&Y[m * N_GEMM + n] = o;
        }
    }
}

// ---------- Kernel 2: causal flash attention, bf16 MFMA 16x16x32 -------------
// Block: 256 threads (4 waves) owns a 64-row Q tile; wave w owns rows
// [q0+16w, q0+16w+16). Per 64-key tile: QK^T = 4 ntiles x 2 ksteps MFMA,
// online softmax in C-layout regs, P->LDS (bf16), PV = 4 dtiles x 2 ksteps.
// V is staged TRANSPOSED in LDS so the PV B-frag is a contiguous b128 read.
// All LDS rows padded to 72 bf16 (144 B, 16B-aligned, stride-conflict break).
#define LPAD 72

__global__ __launch_bounds__(256, 4) void attn_mfma(const float* __restrict__ qkv,
                                                    float* __restrict__ out) {
    const int b = blockIdx.z;
    const int h = blockIdx.y;
    const int qt = gridDim.x - 1 - blockIdx.x;   // heavy tiles first
    const int tid = threadIdx.x;
    const int w = tid >> 6;          // wave 0..3
    const int lane = tid & 63;
    const int quad = lane >> 4;      // 0..3
    const int l16 = lane & 15;       // 0..15
    const int q0 = qt * 64;

    __shared__ short Ks[64][LPAD];        // [key][d]   bf16
    __shared__ short Vt[64][LPAD];        // [d][key]   bf16 (transposed)
    __shared__ short Ps[4][16][LPAD];     // per-wave P strip [qrow][key]

    const float scale = 0.125f;           // 1/sqrt(64)

    // ---- Load Q fragments (A-layout: A[m=l16][k=quad*8+j], k = d) ----
    const float* qrow = qkv + (size_t)(b * SEQ + q0 + w * 16 + l16) * N_GEMM + h * HDIM;
    short8 aq[2];
#pragma unroll
    for (int ks = 0; ks < 2; ++ks) {
        float4 x0 = *(const float4*)(qrow + ks * 32 + quad * 8);
        float4 x1 = *(const float4*)(qrow + ks * 32 + quad * 8 + 4);
        aq[ks][0] = bf16_rn(x0.x); aq[ks][1] = bf16_rn(x0.y);
        aq[ks][2] = bf16_rn(x0.z); aq[ks][3] = bf16_rn(x0.w);
        aq[ks][4] = bf16_rn(x1.x); aq[ks][5] = bf16_rn(x1.y);
        aq[ks][6] = bf16_rn(x1.z); aq[ks][7] = bf16_rn(x1.w);
    }

    float m_run[4], l_run[4];
    f32x4 o_acc[4];                        // [dtile][reg r] rows quad*4+r
#pragma unroll
    for (int r = 0; r < 4; ++r) { m_run[r] = -1e30f; l_run[r] = 0.f; }
#pragma unroll
    for (int dt = 0; dt < 4; ++dt) o_acc[dt] = (f32x4){0.f, 0.f, 0.f, 0.f};

    const int rowg0 = q0 + w * 16 + quad * 4;     // + r = global q row
    const float* kb0 = qkv + (size_t)(b * SEQ) * N_GEMM + CDIM + h * HDIM;

    for (int kt = 0; kt <= qt; ++kt) {
        const float* kbase = kb0 + (size_t)kt * 64 * N_GEMM;
        const float* vbase = kbase + CDIM;

        __syncthreads();   // previous tile's LDS reads complete
        // ---- stage K (row-major) and V (transposed), fp32 -> bf16 ----
#pragma unroll
        for (int pass = 0; pass < 4; ++pass) {
            int i = pass * 256 + tid;     // 0..1023
            int key = i >> 4;             // 0..63
            int d4 = i & 15;              // float4 index
            float4 kv = *(const float4*)(kbase + (size_t)key * N_GEMM + d4 * 4);
            short4v kb;
            kb[0] = bf16_rn(kv.x); kb[1] = bf16_rn(kv.y);
            kb[2] = bf16_rn(kv.z); kb[3] = bf16_rn(kv.w);
            *(short4v*)&Ks[key][d4 * 4] = kb;
            float4 vv = *(const float4*)(vbase + (size_t)key * N_GEMM + d4 * 4);
            Vt[d4 * 4 + 0][key] = bf16_rn(vv.x);
            Vt[d4 * 4 + 1][key] = bf16_rn(vv.y);
            Vt[d4 * 4 + 2][key] = bf16_rn(vv.z);
            Vt[d4 * 4 + 3][key] = bf16_rn(vv.w);
        }
        __syncthreads();

        // ---- QK^T: S[16 q][64 keys], 4 ntiles x 2 ksteps ----
        f32x4 s[4];
#pragma unroll
        for (int nt = 0; nt < 4; ++nt) s[nt] = (f32x4){0.f, 0.f, 0.f, 0.f};
#pragma unroll
        for (int nt = 0; nt < 4; ++nt)
#pragma unroll
            for (int ks = 0; ks < 2; ++ks) {
                short8 bk = *(const short8*)&Ks[nt * 16 + l16][ks * 32 + quad * 8];
                s[nt] = __builtin_amdgcn_mfma_f32_16x16x32_bf16(aq[ks], bk, s[nt], 0, 0, 0);
            }

        // ---- online softmax (C-layout: row=quad*4+r, col=nt*16+l16) ----
        const bool diag = (kt == qt);
        const int keyb = kt * 64 + l16;
        float p[4][4];                     // [nt][r]
#pragma unroll
        for (int r = 0; r < 4; ++r) {
            float mx = -1e30f;
            float sv[4];
#pragma unroll
            for (int nt = 0; nt < 4; ++nt) {
                float v = s[nt][r] * scale;
                if (diag && (keyb + nt * 16) > (rowg0 + r)) v = -1e30f;
                sv[nt] = v;
                mx = fmaxf(mx, v);
            }
#pragma unroll
            for (int off = 1; off < 16; off <<= 1)
                mx = fmaxf(mx, __shfl_xor(mx, off));
            float mnew = fmaxf(m_run[r], mx);
            float corr = __expf(m_run[r] - mnew);
            float lsum = 0.f;
#pragma unroll
            for (int nt = 0; nt < 4; ++nt) {
                float pp = __expf(sv[nt] - mnew);
                p[nt][r] = pp;
                lsum += pp;
            }
#pragma unroll
            for (int off = 1; off < 16; off <<= 1)
                lsum += __shfl_xor(lsum, off);
            l_run[r] = l_run[r] * corr + lsum;
            m_run[r] = mnew;
#pragma unroll
            for (int dt = 0; dt < 4; ++dt) o_acc[dt][r] *= corr;
        }

        // ---- P -> LDS (bf16, A-layout source for PV) ----
#pragma unroll
        for (int r = 0; r < 4; ++r)
#pragma unroll
            for (int nt = 0; nt < 4; ++nt)
                Ps[w][quad * 4 + r][nt * 16 + l16] = bf16_rn(p[nt][r]);
        __syncthreads();   // Ps/Vt writes visible (also keeps waves in step)

        // ---- PV: O[16 q][64 d] += P @ V ----
#pragma unroll
        for (int dt = 0; dt < 4; ++dt)
#pragma unroll
            for (int ks = 0; ks < 2; ++ks) {
                short8 ap = *(const short8*)&Ps[w][l16][ks * 32 + quad * 8];
                short8 bv = *(const short8*)&Vt[dt * 16 + l16][ks * 32 + quad * 8];
                o_acc[dt] = __builtin_amdgcn_mfma_f32_16x16x32_bf16(ap, bv, o_acc[dt], 0, 0, 0);
            }
    }

    // ---- epilogue: normalize and store fp32 ----
#pragma unroll
    for (int r = 0; r < 4; ++r) {
        float inv = 1.f / l_run[r];
        int row = q0 + w * 16 + quad * 4 + r;
        float* optr = out + (size_t)(b * SEQ + row) * CDIM + h * HDIM;
#pragma unroll
        for (int dt = 0; dt < 4; ++dt)
            optr[dt * 16 + l16] = o_acc[dt][r] * inv;
    }
}

// ------------------------------- launch --------------------------------------
extern "C" void kernel_launch(void* const* d_in, const int* in_sizes, int n_in,
                              void* d_out, int out_size, void* d_ws, size_t ws_size,
                              hipStream_t stream) {
    const float* x      = (const float*)d_in[0];   // [B,T,C]
    const float* w_attn = (const float*)d_in[1];   // [C,3C]
    const float* b_attn = (const float*)d_in[2];   // [3C]
    float* out = (float*)d_out;                    // [B,T,C]
    float* qkv = (float*)d_ws;                     // [B,T,3C] scratch

    dim3 g1(N_GEMM / BN, M_GEMM / BM);   // (24, 32)
    qkv_gemm<<<g1, 256, 0, stream>>>(x, w_attn, b_attn, qkv);

    dim3 g2(SEQ / 64, NHEAD, BSZ);       // (32, 16, 2)
    attn_mfma<<<g2, 256, 0, stream>>>(qkv, out);
}

// Round 4
// 280.910 us; speedup vs baseline: 9.4815x; 2.0028x over previous
//
#include <hip/hip_runtime.h>
#include <hip/hip_bf16.h>

// Problem constants: B=2, T=2048, C=1024, H=16, D=64
#define BSZ 2
#define SEQ 2048
#define CDIM 1024
#define NHEAD 16
#define HDIM 64
#define M_GEMM (BSZ * SEQ)      // 4096
#define N_GEMM (3 * CDIM)       // 3072
#define K_GEMM CDIM             // 1024

typedef __attribute__((ext_vector_type(8))) short short8;   // 8 bf16 = 16B
typedef __attribute__((ext_vector_type(4))) float f32x4;

__device__ __forceinline__ short bf16_rn(float f) {
    unsigned u = __builtin_bit_cast(unsigned, f);
    u += 0x7FFF + ((u >> 16) & 1);          // round-to-nearest-even
    return (short)(u >> 16);
}

// async 16B global -> LDS (wave-uniform LDS base + lane*16)
__device__ __forceinline__ void gl2lds16(const short* g, short* l) {
    __builtin_amdgcn_global_load_lds(
        (const __attribute__((address_space(1))) unsigned int*)g,
        (__attribute__((address_space(3))) unsigned int*)l, 16, 0, 0);
}

// ---------------- Kernel 0a: x fp32 -> bf16 (same layout) --------------------
__global__ __launch_bounds__(256) void cvt_x(const float* __restrict__ X,
                                             short* __restrict__ Xb) {
    size_t idx = ((size_t)blockIdx.x * 256 + threadIdx.x) * 8;
    float4 a = *(const float4*)&X[idx];
    float4 b = *(const float4*)&X[idx + 4];
    short8 o;
    o[0] = bf16_rn(a.x); o[1] = bf16_rn(a.y); o[2] = bf16_rn(a.z); o[3] = bf16_rn(a.w);
    o[4] = bf16_rn(b.x); o[5] = bf16_rn(b.y); o[6] = bf16_rn(b.z); o[7] = bf16_rn(b.w);
    *(short8*)&Xb[idx] = o;
}

// ------------- Kernel 0b: W [K][N] fp32 -> W^T [N][K] bf16 (64x64 tiles) -----
__global__ __launch_bounds__(256) void cvt_wT(const float* __restrict__ W,
                                              short* __restrict__ WT) {
    __shared__ short T[64][72];          // [n][k], padded row (144B, 16B-mult)
    const int n0 = blockIdx.x * 64;
    const int k0 = blockIdx.y * 64;
    const int tid = threadIdx.x;
#pragma unroll
    for (int pass = 0; pass < 4; ++pass) {
        int i = pass * 256 + tid;        // 0..1023
        int kr = i >> 4;                 // 0..63
        int n4 = i & 15;
        float4 v = *(const float4*)&W[(size_t)(k0 + kr) * N_GEMM + n0 + n4 * 4];
        T[n4 * 4 + 0][kr] = bf16_rn(v.x);
        T[n4 * 4 + 1][kr] = bf16_rn(v.y);
        T[n4 * 4 + 2][kr] = bf16_rn(v.z);
        T[n4 * 4 + 3][kr] = bf16_rn(v.w);
    }
    __syncthreads();
#pragma unroll
    for (int pass = 0; pass < 2; ++pass) {
        int o = pass * 256 + tid;        // 0..511
        int nr = o >> 3;
        int c8 = o & 7;
        *(short8*)&WT[(size_t)(n0 + nr) * K_GEMM + k0 + c8 * 8] =
            *(const short8*)&T[nr][c8 * 8];
    }
}

// -------- Kernel 1: qkv = x @ W + b, bf16 MFMA 16x16x32 (m97 structure) ------
// 128x128 tile, BK=32, 256 threads (4 waves, each a 64x64 subtile = 4x4 MFMA).
// LDS chunk-swizzled: row r's 16B chunk "cg" lives at slot (cg ^ (r&3)) ->
// global_load_lds-compatible (contiguous chunks) AND conflict-free b128 frag
// reads (uniform 8 accesses/bank = floor).
#define GBK 32

__global__ __launch_bounds__(256) void qkv_gemm_mfma(const short* __restrict__ A,
                                                     const short* __restrict__ Bt,
                                                     const float* __restrict__ bias,
                                                     short* __restrict__ Y) {
    __shared__ short Asl[128 * GBK];     // 8 KB
    __shared__ short Bsl[128 * GBK];     // 8 KB

    const int tid = threadIdx.x;
    const int w = tid >> 6;
    const int l16 = tid & 15;
    const int quad = (tid & 63) >> 4;
    const int wm = w >> 1, wn = w & 1;
    const int m0 = blockIdx.y * 128;
    const int n0 = blockIdx.x * 128;

    f32x4 acc[4][4];
#pragma unroll
    for (int i = 0; i < 4; ++i)
#pragma unroll
        for (int j = 0; j < 4; ++j) acc[i][j] = (f32x4){0.f, 0.f, 0.f, 0.f};

    // staging: chunk cid = pass*256 + tid; row=cid>>2, slot=cid&3,
    // global chunk col = slot ^ (row&3)
    const int cid0 = tid, cid1 = 256 + tid;
    const int ar0 = cid0 >> 2, as0 = (cid0 & 3) ^ (ar0 & 3);
    const int ar1 = cid1 >> 2, as1 = (cid1 & 3) ^ (ar1 & 3);
    const short* Ap0 = A + (size_t)(m0 + ar0) * K_GEMM + as0 * 8;
    const short* Ap1 = A + (size_t)(m0 + ar1) * K_GEMM + as1 * 8;
    const short* Bp0 = Bt + (size_t)(n0 + ar0) * K_GEMM + as0 * 8;
    const short* Bp1 = Bt + (size_t)(n0 + ar1) * K_GEMM + as1 * 8;
    short* Al0 = &Asl[(w * 64) * 8];         // wave-uniform LDS bases
    short* Al1 = &Asl[(256 + w * 64) * 8];
    short* Bl0 = &Bsl[(w * 64) * 8];
    short* Bl1 = &Bsl[(256 + w * 64) * 8];

    const int fsw = quad ^ (l16 & 3);        // frag-read swizzle slot

    for (int kt = 0; kt < K_GEMM; kt += GBK) {
        __syncthreads();                     // prev iter's frag reads done
        gl2lds16(Ap0 + kt, Al0);
        gl2lds16(Ap1 + kt, Al1);
        gl2lds16(Bp0 + kt, Bl0);
        gl2lds16(Bp1 + kt, Bl1);
        __syncthreads();                     // staging complete (vmcnt drain)

        short8 af[4], bfr[4];
#pragma unroll
        for (int i = 0; i < 4; ++i) {
            int r = wm * 64 + i * 16 + l16;
            af[i] = *(const short8*)&Asl[(r * 4 + fsw) * 8];
        }
#pragma unroll
        for (int j = 0; j < 4; ++j) {
            int r = wn * 64 + j * 16 + l16;
            bfr[j] = *(const short8*)&Bsl[(r * 4 + fsw) * 8];
        }
#pragma unroll
        for (int i = 0; i < 4; ++i)
#pragma unroll
            for (int j = 0; j < 4; ++j)
                acc[i][j] = __builtin_amdgcn_mfma_f32_16x16x32_bf16(
                    af[i], bfr[j], acc[i][j], 0, 0, 0);
    }

    // epilogue: C/D layout col=l16, row=quad*4+r ; add bias, store bf16
#pragma unroll
    for (int i = 0; i < 4; ++i)
#pragma unroll
        for (int r = 0; r < 4; ++r) {
            int row = m0 + wm * 64 + i * 16 + quad * 4 + r;
#pragma unroll
            for (int j = 0; j < 4; ++j) {
                int col = n0 + wn * 64 + j * 16 + l16;
                float v = acc[i][j][r] + bias[col];
                Y[(size_t)row * N_GEMM + col] = bf16_rn(v);
            }
        }
}

// ---------- Kernel 2: causal flash attention, bf16 MFMA 16x16x32 -------------
// Same verified structure as R3, but qkv is now bf16 (half the staging bytes,
// no cvt in the load path).
#define LPAD 72

__global__ __launch_bounds__(256, 4) void attn_mfma(const short* __restrict__ qkv,
                                                    float* __restrict__ out) {
    const int b = blockIdx.z;
    const int h = blockIdx.y;
    const int qt = gridDim.x - 1 - blockIdx.x;   // heavy tiles first
    const int tid = threadIdx.x;
    const int w = tid >> 6;
    const int lane = tid & 63;
    const int quad = lane >> 4;
    const int l16 = lane & 15;
    const int q0 = qt * 64;

    __shared__ short Ks[64][LPAD];        // [key][d]
    __shared__ short Vt[64][LPAD];        // [d][key] (transposed)
    __shared__ short Ps[4][16][LPAD];     // per-wave P strip

    const float scale = 0.125f;

    // Q fragments (A-layout), direct bf16 16B loads
    const short* qrow = qkv + (size_t)(b * SEQ + q0 + w * 16 + l16) * N_GEMM + h * HDIM;
    short8 aq[2];
    aq[0] = *(const short8*)(qrow + quad * 8);
    aq[1] = *(const short8*)(qrow + 32 + quad * 8);

    float m_run[4], l_run[4];
    f32x4 o_acc[4];
#pragma unroll
    for (int r = 0; r < 4; ++r) { m_run[r] = -1e30f; l_run[r] = 0.f; }
#pragma unroll
    for (int dt = 0; dt < 4; ++dt) o_acc[dt] = (f32x4){0.f, 0.f, 0.f, 0.f};

    const int rowg0 = q0 + w * 16 + quad * 4;
    const short* kb0 = qkv + (size_t)(b * SEQ) * N_GEMM + CDIM + h * HDIM;

    for (int kt = 0; kt <= qt; ++kt) {
        const short* kbase = kb0 + (size_t)kt * 64 * N_GEMM;
        const short* vbase = kbase + CDIM;

        __syncthreads();
#pragma unroll
        for (int pass = 0; pass < 2; ++pass) {
            int cid = pass * 256 + tid;   // 0..511
            int key = cid >> 3;
            int d8 = cid & 7;
            short8 kv = *(const short8*)(kbase + (size_t)key * N_GEMM + d8 * 8);
            *(short8*)&Ks[key][d8 * 8] = kv;
            short8 vv = *(const short8*)(vbase + (size_t)key * N_GEMM + d8 * 8);
#pragma unroll
            for (int e = 0; e < 8; ++e) Vt[d8 * 8 + e][key] = vv[e];
        }
        __syncthreads();

        // QK^T
        f32x4 s[4];
#pragma unroll
        for (int nt = 0; nt < 4; ++nt) s[nt] = (f32x4){0.f, 0.f, 0.f, 0.f};
#pragma unroll
        for (int nt = 0; nt < 4; ++nt)
#pragma unroll
            for (int ks = 0; ks < 2; ++ks) {
                short8 bk = *(const short8*)&Ks[nt * 16 + l16][ks * 32 + quad * 8];
                s[nt] = __builtin_amdgcn_mfma_f32_16x16x32_bf16(aq[ks], bk, s[nt], 0, 0, 0);
            }

        // online softmax (C-layout row=quad*4+r, col=nt*16+l16)
        const bool diag = (kt == qt);
        const int keyb = kt * 64 + l16;
        float p[4][4];
#pragma unroll
        for (int r = 0; r < 4; ++r) {
            float mx = -1e30f;
            float sv[4];
#pragma unroll
            for (int nt = 0; nt < 4; ++nt) {
                float v = s[nt][r] * scale;
                if (diag && (keyb + nt * 16) > (rowg0 + r)) v = -1e30f;
                sv[nt] = v;
                mx = fmaxf(mx, v);
            }
#pragma unroll
            for (int off = 1; off < 16; off <<= 1)
                mx = fmaxf(mx, __shfl_xor(mx, off));
            float mnew = fmaxf(m_run[r], mx);
            float corr = __expf(m_run[r] - mnew);
            float lsum = 0.f;
#pragma unroll
            for (int nt = 0; nt < 4; ++nt) {
                float pp = __expf(sv[nt] - mnew);
                p[nt][r] = pp;
                lsum += pp;
            }
#pragma unroll
            for (int off = 1; off < 16; off <<= 1)
                lsum += __shfl_xor(lsum, off);
            l_run[r] = l_run[r] * corr + lsum;
            m_run[r] = mnew;
#pragma unroll
            for (int dt = 0; dt < 4; ++dt) o_acc[dt][r] *= corr;
        }

        // P -> LDS (A-layout source for PV)
#pragma unroll
        for (int r = 0; r < 4; ++r)
#pragma unroll
            for (int nt = 0; nt < 4; ++nt)
                Ps[w][quad * 4 + r][nt * 16 + l16] = bf16_rn(p[nt][r]);
        __syncthreads();

        // PV
#pragma unroll
        for (int dt = 0; dt < 4; ++dt)
#pragma unroll
            for (int ks = 0; ks < 2; ++ks) {
                short8 ap = *(const short8*)&Ps[w][l16][ks * 32 + quad * 8];
                short8 bv = *(const short8*)&Vt[dt * 16 + l16][ks * 32 + quad * 8];
                o_acc[dt] = __builtin_amdgcn_mfma_f32_16x16x32_bf16(ap, bv, o_acc[dt], 0, 0, 0);
            }
    }

    // epilogue
#pragma unroll
    for (int r = 0; r < 4; ++r) {
        float inv = 1.f / l_run[r];
        int row = q0 + w * 16 + quad * 4 + r;
        float* optr = out + (size_t)(b * SEQ + row) * CDIM + h * HDIM;
#pragma unroll
        for (int dt = 0; dt < 4; ++dt)
            optr[dt * 16 + l16] = o_acc[dt][r] * inv;
    }
}

// ------------------------------- launch --------------------------------------
extern "C" void kernel_launch(void* const* d_in, const int* in_sizes, int n_in,
                              void* d_out, int out_size, void* d_ws, size_t ws_size,
                              hipStream_t stream) {
    const float* x      = (const float*)d_in[0];   // [B,T,C] fp32
    const float* w_attn = (const float*)d_in[1];   // [C,3C]  fp32
    const float* b_attn = (const float*)d_in[2];   // [3C]    fp32
    float* out = (float*)d_out;                    // [B,T,C] fp32

    // workspace layout (bytes): qkv_bf16 25,165,824 | x_bf16 8,388,608 | wT 6,291,456
    short* qkv = (short*)d_ws;
    short* xb  = (short*)((char*)d_ws + 25165824);
    short* wT  = (short*)((char*)d_ws + 33554432);

    cvt_x<<<M_GEMM * K_GEMM / 2048, 256, 0, stream>>>(x, xb);          // 2048 blocks
    dim3 gt(N_GEMM / 64, K_GEMM / 64);                                  // (48,16)
    cvt_wT<<<gt, 256, 0, stream>>>(w_attn, wT);

    dim3 g1(N_GEMM / 128, M_GEMM / 128);                                // (24,32)
    qkv_gemm_mfma<<<g1, 256, 0, stream>>>(xb, wT, b_attn, qkv);

    dim3 g2(SEQ / 64, NHEAD, BSZ);                                      // (32,16,2)
    attn_mfma<<<g2, 256, 0, stream>>>(qkv, out);
}

// Round 5
// 215.656 us; speedup vs baseline: 12.3504x; 1.3026x over previous
//
#include <hip/hip_runtime.h>
#include <hip/hip_bf16.h>

// Problem constants: B=2, T=2048, C=1024, H=16, D=64
#define BSZ 2
#define SEQ 2048
#define CDIM 1024
#define NHEAD 16
#define HDIM 64
#define M_GEMM (BSZ * SEQ)      // 4096
#define N_GEMM (3 * CDIM)       // 3072
#define K_GEMM CDIM             // 1024
#define QK_PITCH (2 * CDIM)     // 2048: qkv_qk row pitch (Q|K only)

typedef __attribute__((ext_vector_type(8))) short short8;   // 8 bf16 = 16B
typedef __attribute__((ext_vector_type(4))) short short4v;  // 8B
typedef __attribute__((ext_vector_type(4))) float f32x4;

__device__ __forceinline__ short bf16_rn(float f) {
    unsigned u = __builtin_bit_cast(unsigned, f);
    u += 0x7FFF + ((u >> 16) & 1);          // round-to-nearest-even
    return (short)(u >> 16);
}

// async 16B global -> LDS (wave-uniform LDS base; HW adds lane*16)
__device__ __forceinline__ void gl2lds16(const short* g, short* l) {
    __builtin_amdgcn_global_load_lds(
        (const __attribute__((address_space(1))) unsigned int*)g,
        (__attribute__((address_space(3))) unsigned int*)l, 16, 0, 0);
}

// ---------------- Kernel 0a: x fp32 -> bf16 (same layout) --------------------
__global__ __launch_bounds__(256) void cvt_x(const float* __restrict__ X,
                                             short* __restrict__ Xb) {
    size_t idx = ((size_t)blockIdx.x * 256 + threadIdx.x) * 8;
    float4 a = *(const float4*)&X[idx];
    float4 b = *(const float4*)&X[idx + 4];
    short8 o;
    o[0] = bf16_rn(a.x); o[1] = bf16_rn(a.y); o[2] = bf16_rn(a.z); o[3] = bf16_rn(a.w);
    o[4] = bf16_rn(b.x); o[5] = bf16_rn(b.y); o[6] = bf16_rn(b.z); o[7] = bf16_rn(b.w);
    *(short8*)&Xb[idx] = o;
}

// ------------- Kernel 0b: W [K][N] fp32 -> W^T [N][K] bf16 (64x64 tiles) -----
__global__ __launch_bounds__(256) void cvt_wT(const float* __restrict__ W,
                                              short* __restrict__ WT) {
    __shared__ short T[64][72];          // [n][k], padded row
    const int n0 = blockIdx.x * 64;
    const int k0 = blockIdx.y * 64;
    const int tid = threadIdx.x;
#pragma unroll
    for (int pass = 0; pass < 4; ++pass) {
        int i = pass * 256 + tid;
        int kr = i >> 4;
        int n4 = i & 15;
        float4 v = *(const float4*)&W[(size_t)(k0 + kr) * N_GEMM + n0 + n4 * 4];
        T[n4 * 4 + 0][kr] = bf16_rn(v.x);
        T[n4 * 4 + 1][kr] = bf16_rn(v.y);
        T[n4 * 4 + 2][kr] = bf16_rn(v.z);
        T[n4 * 4 + 3][kr] = bf16_rn(v.w);
    }
    __syncthreads();
#pragma unroll
    for (int pass = 0; pass < 2; ++pass) {
        int o = pass * 256 + tid;
        int nr = o >> 3;
        int c8 = o & 7;
        *(short8*)&WT[(size_t)(n0 + nr) * K_GEMM + k0 + c8 * 8] =
            *(const short8*)&T[nr][c8 * 8];
    }
}

// -------- Kernel 1: qkv = x @ W + b, bf16 MFMA 16x16x32 (m97 structure) ------
// Q,K cols (<2048) -> Yqk [4096][2048]; V cols (>=2048) -> Yv TRANSPOSED
// [1024][4096] so attention can stage V with vectorized, conflict-free loads.
#define GBK 32

__global__ __launch_bounds__(256) void qkv_gemm_mfma(const short* __restrict__ A,
                                                     const short* __restrict__ Bt,
                                                     const float* __restrict__ bias,
                                                     short* __restrict__ Yqk,
                                                     short* __restrict__ Yv) {
    __shared__ short Asl[128 * GBK];     // 8 KB
    __shared__ short Bsl[128 * GBK];     // 8 KB

    const int tid = threadIdx.x;
    const int w = tid >> 6;
    const int l16 = tid & 15;
    const int quad = (tid & 63) >> 4;
    const int wm = w >> 1, wn = w & 1;
    const int m0 = blockIdx.y * 128;
    const int n0 = blockIdx.x * 128;

    f32x4 acc[4][4];
#pragma unroll
    for (int i = 0; i < 4; ++i)
#pragma unroll
        for (int j = 0; j < 4; ++j) acc[i][j] = (f32x4){0.f, 0.f, 0.f, 0.f};

    const int cid0 = tid, cid1 = 256 + tid;
    const int ar0 = cid0 >> 2, as0 = (cid0 & 3) ^ (ar0 & 3);
    const int ar1 = cid1 >> 2, as1 = (cid1 & 3) ^ (ar1 & 3);
    const short* Ap0 = A + (size_t)(m0 + ar0) * K_GEMM + as0 * 8;
    const short* Ap1 = A + (size_t)(m0 + ar1) * K_GEMM + as1 * 8;
    const short* Bp0 = Bt + (size_t)(n0 + ar0) * K_GEMM + as0 * 8;
    const short* Bp1 = Bt + (size_t)(n0 + ar1) * K_GEMM + as1 * 8;
    short* Al0 = &Asl[(w * 64) * 8];
    short* Al1 = &Asl[(256 + w * 64) * 8];
    short* Bl0 = &Bsl[(w * 64) * 8];
    short* Bl1 = &Bsl[(256 + w * 64) * 8];

    const int fsw = quad ^ (l16 & 3);

    for (int kt = 0; kt < K_GEMM; kt += GBK) {
        __syncthreads();
        gl2lds16(Ap0 + kt, Al0);
        gl2lds16(Ap1 + kt, Al1);
        gl2lds16(Bp0 + kt, Bl0);
        gl2lds16(Bp1 + kt, Bl1);
        __syncthreads();

        short8 af[4], bfr[4];
#pragma unroll
        for (int i = 0; i < 4; ++i) {
            int r = wm * 64 + i * 16 + l16;
            af[i] = *(const short8*)&Asl[(r * 4 + fsw) * 8];
        }
#pragma unroll
        for (int j = 0; j < 4; ++j) {
            int r = wn * 64 + j * 16 + l16;
            bfr[j] = *(const short8*)&Bsl[(r * 4 + fsw) * 8];
        }
#pragma unroll
        for (int i = 0; i < 4; ++i)
#pragma unroll
            for (int j = 0; j < 4; ++j)
                acc[i][j] = __builtin_amdgcn_mfma_f32_16x16x32_bf16(
                    af[i], bfr[j], acc[i][j], 0, 0, 0);
    }

    if (n0 >= 2 * CDIM) {
        // V block: write transposed, 4 consecutive rows packed per 8B store
#pragma unroll
        for (int i = 0; i < 4; ++i) {
            int row0 = m0 + wm * 64 + i * 16 + quad * 4;
#pragma unroll
            for (int j = 0; j < 4; ++j) {
                int colg = n0 + wn * 64 + j * 16 + l16;
                float bb = bias[colg];
                short4v pk;
#pragma unroll
                for (int r = 0; r < 4; ++r) pk[r] = bf16_rn(acc[i][j][r] + bb);
                *(short4v*)&Yv[(size_t)(colg - 2 * CDIM) * M_GEMM + row0] = pk;
            }
        }
    } else {
#pragma unroll
        for (int i = 0; i < 4; ++i)
#pragma unroll
            for (int r = 0; r < 4; ++r) {
                int row = m0 + wm * 64 + i * 16 + quad * 4 + r;
#pragma unroll
                for (int j = 0; j < 4; ++j) {
                    int colg = n0 + wn * 64 + j * 16 + l16;
                    Yqk[(size_t)row * QK_PITCH + colg] = bf16_rn(acc[i][j][r] + bias[colg]);
                }
            }
    }
}

// ---------- Kernel 2: causal flash attention, bf16 MFMA, swizzled LDS --------
// XOR chunk swizzle: 16B chunk c of row r lives at slot c^(r&7). Staging via
// global_load_lds (contiguous chunks), all b128 frag reads conflict-free.
// Ps is wave-private (no barrier between write and PV read).
__global__ __launch_bounds__(256, 4) void attn_mfma(const short* __restrict__ qk,
                                                    const short* __restrict__ vT,
                                                    float* __restrict__ out) {
    const int b = blockIdx.z;
    const int h = blockIdx.y;
    const int qt = gridDim.x - 1 - blockIdx.x;   // heavy tiles first
    const int tid = threadIdx.x;
    const int w = tid >> 6;
    const int lane = tid & 63;
    const int quad = lane >> 4;
    const int l16 = lane & 15;
    const int q0 = qt * 64;

    __shared__ short Ks[64 * 64];        // [key][d], chunk-swizzled   8 KB
    __shared__ short Vt[64 * 64];        // [d][key], chunk-swizzled   8 KB
    __shared__ short Ps[4 * 16 * 64];    // per-wave [q][key], swizzled 8 KB

    const float scale = 0.125f;

    // staging descriptors: issue p covers chunks cid = p*256 + w*64 + lane
    int koff[2], voff[2];
    short *ksb[2], *vtb[2];
#pragma unroll
    for (int p = 0; p < 2; ++p) {
        int cid = p * 256 + w * 64 + lane;
        int row = cid >> 3;                       // key (K) or d (V)
        int c = (cid & 7) ^ (row & 7);            // global chunk for this slot
        koff[p] = row * QK_PITCH + c * 8;
        voff[p] = row * M_GEMM + c * 8;
        ksb[p] = &Ks[(p * 256 + w * 64) * 8];
        vtb[p] = &Vt[(p * 256 + w * 64) * 8];
    }

    // Q fragments (A-layout: A[m=l16][k=quad*8+j])
    const short* qrow = qk + (size_t)(b * SEQ + q0 + w * 16 + l16) * QK_PITCH + h * HDIM;
    short8 aq[2];
    aq[0] = *(const short8*)(qrow + quad * 8);
    aq[1] = *(const short8*)(qrow + 32 + quad * 8);

    float m_run[4], l_run[4];
    f32x4 o_acc[4];
#pragma unroll
    for (int r = 0; r < 4; ++r) { m_run[r] = -1e30f; l_run[r] = 0.f; }
#pragma unroll
    for (int dt = 0; dt < 4; ++dt) o_acc[dt] = (f32x4){0.f, 0.f, 0.f, 0.f};

    const int rowg0 = q0 + w * 16 + quad * 4;
    const short* kb0 = qk + (size_t)(b * SEQ) * QK_PITCH + CDIM + h * HDIM;
    const short* vb0 = vT + (size_t)(h * HDIM) * M_GEMM + b * SEQ;

    const int ksl = l16 & 7;            // frag-read swizzle component
    short* PsW = &Ps[w * 1024];         // wave-private P strip

    for (int kt = 0; kt <= qt; ++kt) {
        const short* kbase = kb0 + (size_t)kt * 64 * QK_PITCH;
        const short* vbase = vb0 + kt * 64;

        __syncthreads();                 // prior tile's Ks/Vt reads complete
        gl2lds16(kbase + koff[0], ksb[0]);
        gl2lds16(kbase + koff[1], ksb[1]);
        gl2lds16(vbase + voff[0], vtb[0]);
        gl2lds16(vbase + voff[1], vtb[1]);
        __syncthreads();                 // staging drained (vmcnt before barrier)

        // ---- QK^T: S[16 q][64 keys] ----
        f32x4 s[4];
#pragma unroll
        for (int nt = 0; nt < 4; ++nt) s[nt] = (f32x4){0.f, 0.f, 0.f, 0.f};
#pragma unroll
        for (int nt = 0; nt < 4; ++nt)
#pragma unroll
            for (int ks = 0; ks < 2; ++ks) {
                short8 bk = *(const short8*)&Ks[(nt * 16 + l16) * 64 +
                                                (((ks * 4 + quad) ^ ksl)) * 8];
                s[nt] = __builtin_amdgcn_mfma_f32_16x16x32_bf16(aq[ks], bk, s[nt], 0, 0, 0);
            }

        // ---- online softmax (row=quad*4+r, col=nt*16+l16); l is lane-local ----
        const bool diag = (kt == qt);
        const int keyb = kt * 64 + l16;
        float p[4][4];
#pragma unroll
        for (int r = 0; r < 4; ++r) {
            float mx = -1e30f;
            float sv[4];
#pragma unroll
            for (int nt = 0; nt < 4; ++nt) {
                float v = s[nt][r] * scale;
                if (diag && (keyb + nt * 16) > (rowg0 + r)) v = -1e30f;
                sv[nt] = v;
                mx = fmaxf(mx, v);
            }
#pragma unroll
            for (int off = 1; off < 16; off <<= 1)
                mx = fmaxf(mx, __shfl_xor(mx, off));
            float mnew = fmaxf(m_run[r], mx);
            float corr = __expf(m_run[r] - mnew);
            float lsum = 0.f;
#pragma unroll
            for (int nt = 0; nt < 4; ++nt) {
                float pp = __expf(sv[nt] - mnew);
                p[nt][r] = pp;
                lsum += pp;
            }
            l_run[r] = l_run[r] * corr + lsum;   // lane-local; reduced in epilogue
            m_run[r] = mnew;
#pragma unroll
            for (int dt = 0; dt < 4; ++dt) o_acc[dt][r] *= corr;
        }

        // ---- P -> wave-private LDS (swizzled); no barrier needed ----
#pragma unroll
        for (int r = 0; r < 4; ++r) {
            int qr = quad * 4 + r;
#pragma unroll
            for (int nt = 0; nt < 4; ++nt) {
                int slot = (nt * 2 + (l16 >> 3)) ^ (qr & 7);
                PsW[qr * 64 + slot * 8 + (l16 & 7)] = bf16_rn(p[nt][r]);
            }
        }

        // ---- PV: O[16 q][64 d] += P @ V ----
#pragma unroll
        for (int dt = 0; dt < 4; ++dt)
#pragma unroll
            for (int ks = 0; ks < 2; ++ks) {
                short8 ap = *(const short8*)&PsW[l16 * 64 + (((ks * 4 + quad) ^ ksl)) * 8];
                short8 bv = *(const short8*)&Vt[(dt * 16 + l16) * 64 +
                                                (((ks * 4 + quad) ^ ksl)) * 8];
                o_acc[dt] = __builtin_amdgcn_mfma_f32_16x16x32_bf16(ap, bv, o_acc[dt], 0, 0, 0);
            }
    }

    // ---- epilogue: reduce l across the 16 row lanes, normalize, store ----
#pragma unroll
    for (int r = 0; r < 4; ++r) {
        float l = l_run[r];
#pragma unroll
        for (int off = 1; off < 16; off <<= 1)
            l += __shfl_xor(l, off);
        float inv = 1.f / l;
        int row = q0 + w * 16 + quad * 4 + r;
        float* optr = out + (size_t)(b * SEQ + row) * CDIM + h * HDIM;
#pragma unroll
        for (int dt = 0; dt < 4; ++dt)
            optr[dt * 16 + l16] = o_acc[dt][r] * inv;
    }
}

// ------------------------------- launch --------------------------------------
extern "C" void kernel_launch(void* const* d_in, const int* in_sizes, int n_in,
                              void* d_out, int out_size, void* d_ws, size_t ws_size,
                              hipStream_t stream) {
    const float* x      = (const float*)d_in[0];   // [B,T,C] fp32
    const float* w_attn = (const float*)d_in[1];   // [C,3C]  fp32
    const float* b_attn = (const float*)d_in[2];   // [3C]    fp32
    float* out = (float*)d_out;                    // [B,T,C] fp32

    // workspace: qk [4096][2048] 16.78MB | vT [1024][4096] 8.39MB | xb 8.39MB | wT 6.29MB
    short* qk  = (short*)d_ws;
    short* vT  = (short*)((char*)d_ws + 16777216);
    short* xb  = (short*)((char*)d_ws + 25165824);
    short* wT  = (short*)((char*)d_ws + 33554432);

    cvt_x<<<M_GEMM * K_GEMM / 2048, 256, 0, stream>>>(x, xb);
    dim3 gt(N_GEMM / 64, K_GEMM / 64);                                  // (48,16)
    cvt_wT<<<gt, 256, 0, stream>>>(w_attn, wT);

    dim3 g1(N_GEMM / 128, M_GEMM / 128);                                // (24,32)
    qkv_gemm_mfma<<<g1, 256, 0, stream>>>(xb, wT, b_attn, qk, vT);

    dim3 g2(SEQ / 64, NHEAD, BSZ);                                      // (32,16,2)
    attn_mfma<<<g2, 256, 0, stream>>>(qk, vT, out);
}